// Round 13
// baseline (266.897 us; speedup 1.0000x reference)
//
#include <hip/hip_runtime.h>
#include <hip/hip_bf16.h>
#include <math.h>

// ---------------------------------------------------------------------------
// MEASUREMENT ROUND: exact round-8 pipeline (66.3us), but attn_proj and
// attn_head are each launched 9x (both idempotent: pure functions of their
// inputs; attn_head's atomicMax re-applies the same value).
//   dur = 66.3 + 8 * (T_ap + T_ah + 2*gap)   -> pins the attention pair.
// Known: T_filter = 19.4us (r11 rep-4), node+gap marginal = 20.5us (r9).
// ---------------------------------------------------------------------------

#define B 2
#define N 1024          // 32x32 patches
#define HW 512
#define IMG (HW*HW)

// ---- K1: patchify + QKV projection ---------------------------------------
__global__ __launch_bounds__(256)
void qkv_kernel(const float* __restrict__ x,
                const float* __restrict__ Wq, const float* __restrict__ bq,
                const float* __restrict__ Wk, const float* __restrict__ bk,
                const float* __restrict__ Wv, const float* __restrict__ bv,
                float* __restrict__ Q, float* __restrict__ K, float* __restrict__ V,
                unsigned int* __restrict__ maxbits) {
    const int bn = blockIdx.x;
    const int b  = bn >> 10, n = bn & 1023;
    const int ph = n >> 5, pw = n & 31;
    const int tid = threadIdx.x;
    if (bn == 0 && tid == 0) atomicExch(maxbits, 0u);   // fresh every call
    __shared__ float p[256];
    p[tid] = x[b * IMG + (ph * 16 + (tid >> 4)) * HW + pw * 16 + (tid & 15)];
    __syncthreads();
    if (tid < 192) {
        const int o = tid >> 3, sub = tid & 7;   // 24 outputs x 8 partials
        const int mat = o >> 3, j = o & 7;       // wave-uniform mat
        const float* W  = (mat == 0) ? Wq : (mat == 1) ? Wk : Wv;
        const float* bb = (mat == 0) ? bq : (mat == 1) ? bk : bv;
        float sum = 0.f;
#pragma unroll
        for (int dd = 0; dd < 32; ++dd) {
            const int d = dd * 8 + sub;
            sum = fmaf(p[d], W[d * 8 + j], sum);
        }
        sum += __shfl_xor(sum, 1);
        sum += __shfl_xor(sum, 2);
        sum += __shfl_xor(sum, 4);
        if (sub == 0) {
            float* op = (mat == 0) ? Q : (mat == 1) ? K : V;
            op[bn * 8 + j] = sum + bb[j];
        }
    }
}

// ---- shared LDS-staged attention core (proven round 6/8) -------------------
__device__ __forceinline__ void attn_lds(const float* __restrict__ Qg,
                                         const float* __restrict__ Kb,
                                         const float* __restrict__ Vb,
                                         float* __restrict__ Kl, float* __restrict__ Vl,
                                         int qa, int qb, int tid, int lane,
                                         float fa[8], float fb[8]) {
    for (int i = tid; i < 2048; i += 256) {
        const float4 kv = ((const float4*)Kb)[i];
        const int tok = i >> 1, d0 = (i & 1) * 4;
        Kl[(d0 + 0) * 1024 + tok] = kv.x;
        Kl[(d0 + 1) * 1024 + tok] = kv.y;
        Kl[(d0 + 2) * 1024 + tok] = kv.z;
        Kl[(d0 + 3) * 1024 + tok] = kv.w;
        const float4 vv = ((const float4*)Vb)[i];
        Vl[(d0 + 0) * 1024 + tok] = vv.x;
        Vl[(d0 + 1) * 1024 + tok] = vv.y;
        Vl[(d0 + 2) * 1024 + tok] = vv.z;
        Vl[(d0 + 3) * 1024 + tok] = vv.w;
    }
    __syncthreads();

    float qav[8], qbv[8];
#pragma unroll
    for (int d = 0; d < 8; ++d) { qav[d] = Qg[qa * 8 + d]; qbv[d] = Qg[qb * 8 + d]; }

    const float SC = 0.35355339059327373f;     // 8^-0.5
    const float L2E = 1.4426950408889634f;

    float mxa = -3.0e38f, mxb = -3.0e38f;
#pragma unroll
    for (int t = 0; t < 16; ++t) {
        const int tok = t * 64 + lane;
        float da = 0.f, db = 0.f;
#pragma unroll
        for (int d = 0; d < 8; ++d) {
            const float kd = Kl[d * 1024 + tok];
            da = fmaf(qav[d], kd, da);
            db = fmaf(qbv[d], kd, db);
        }
        mxa = fmaxf(mxa, da); mxb = fmaxf(mxb, db);
    }
#pragma unroll
    for (int off = 1; off < 64; off <<= 1) {
        mxa = fmaxf(mxa, __shfl_xor(mxa, off));
        mxb = fmaxf(mxb, __shfl_xor(mxb, off));
    }
    mxa *= SC; mxb *= SC;

    float sa = 0.f, sb = 0.f;
    float va[8] = {0,0,0,0,0,0,0,0}, vb[8] = {0,0,0,0,0,0,0,0};
#pragma unroll
    for (int t = 0; t < 16; ++t) {
        const int tok = t * 64 + lane;
        float da = 0.f, db = 0.f;
#pragma unroll
        for (int d = 0; d < 8; ++d) {
            const float kd = Kl[d * 1024 + tok];
            da = fmaf(qav[d], kd, da);
            db = fmaf(qbv[d], kd, db);
        }
        const float ea = exp2f((da * SC - mxa) * L2E);
        const float eb = exp2f((db * SC - mxb) * L2E);
        sa += ea; sb += eb;
#pragma unroll
        for (int d = 0; d < 8; ++d) {
            const float vd = Vl[d * 1024 + tok];
            va[d] = fmaf(ea, vd, va[d]);
            vb[d] = fmaf(eb, vd, vb[d]);
        }
    }
#pragma unroll
    for (int off = 1; off < 64; off <<= 1) {
        sa += __shfl_xor(sa, off);
        sb += __shfl_xor(sb, off);
#pragma unroll
        for (int d = 0; d < 8; ++d) {
            va[d] += __shfl_xor(va[d], off);
            vb[d] += __shfl_xor(vb[d], off);
        }
    }
    const float ia = 1.f / sa, ib = 1.f / sb;
#pragma unroll
    for (int d = 0; d < 8; ++d) { fa[d] = va[d] * ia; fb[d] = vb[d] * ib; }
}

// ---- K2: attention #1 + fused second-stage QKV projection -----------------
__global__ __launch_bounds__(256)
void attn_proj_kernel(const float* __restrict__ Q, const float* __restrict__ K,
                      const float* __restrict__ V,
                      const float* __restrict__ Wsq, const float* __restrict__ bsq,
                      const float* __restrict__ Wsk, const float* __restrict__ bsk,
                      const float* __restrict__ Wsv, const float* __restrict__ bsv,
                      float* __restrict__ SQ, float* __restrict__ SK, float* __restrict__ SV) {
    __shared__ float Kl[8 * 1024];
    __shared__ float Vl[8 * 1024];
    const int tid = threadIdx.x, wid = tid >> 6, lane = tid & 63;
    const int q0 = blockIdx.x * 8;            // 8 queries per block, same batch
    const int b  = q0 >> 10;
    const int qa = q0 + wid * 2, qb = qa + 1;
    float fa[8], fb[8];
    attn_lds(Q, K + (b << 13), V + (b << 13), Kl, Vl, qa, qb, tid, lane, fa, fb);
    const int sl = lane & 31;
    if (sl < 24) {
        const int mat = sl >> 3, j = sl & 7;
        const float* W  = (mat == 0) ? Wsq : (mat == 1) ? Wsk : Wsv;
        const float* bb = (mat == 0) ? bsq : (mat == 1) ? bsk : bsv;
        const float* f  = (lane < 32) ? fa : fb;
        const int bn    = (lane < 32) ? qa : qb;
        float o = bb[j];
#pragma unroll
        for (int d = 0; d < 8; ++d) o = fmaf(f[d], W[d * 8 + j], o);
        float* op = (mat == 0) ? SQ : (mat == 1) ? SK : SV;
        op[bn * 8 + j] = o;
    }
}

// ---- K3: attention #2 + fused LN + sigma head + global max ----------------
__global__ __launch_bounds__(256)
void attn_head_kernel(const float* __restrict__ SQ, const float* __restrict__ SK,
                      const float* __restrict__ SV,
                      const float* __restrict__ g, const float* __restrict__ be,
                      const float* __restrict__ Wp, const float* __restrict__ bp,
                      float* __restrict__ SP, unsigned int* __restrict__ maxbits) {
    __shared__ float Kl[8 * 1024];
    __shared__ float Vl[8 * 1024];
    const int tid = threadIdx.x, wid = tid >> 6, lane = tid & 63;
    const int q0 = blockIdx.x * 8;
    const int b  = q0 >> 10;
    const int qa = q0 + wid * 2, qb = qa + 1;
    float fa[8], fb[8];
    attn_lds(SQ, SK + (b << 13), SV + (b << 13), Kl, Vl, qa, qb, tid, lane, fa, fb);

    const float* f = (lane < 32) ? fa : fb;
    const int bn   = (lane < 32) ? qa : qb;
    float mu = 0.f;
#pragma unroll
    for (int d = 0; d < 8; ++d) mu += f[d];
    mu *= 0.125f;
    float var = 0.f;
#pragma unroll
    for (int d = 0; d < 8; ++d) { const float t = f[d] - mu; var = fmaf(t, t, var); }
    var *= 0.125f;
    const float inv = rsqrtf(var + 1e-5f);
    const int sl = lane & 31;
    float val = 0.f;
    if (sl < 3) {
        float o = bp[sl];
#pragma unroll
        for (int d = 0; d < 8; ++d) {
            const float nrm = (f[d] - mu) * inv * g[d] + be[d];
            o = fmaf(nrm, Wp[d * 3 + sl], o);
        }
        const float sp = fmaxf(o, 0.f) + log1pf(__expf(-fabsf(o)));
        const float v = fminf(sp, 6.0f) + 1e-6f;
        SP[bn * 3 + sl] = v;
        val = (sl < 2) ? v : 0.f;    // only sx, sy feed the kernel-size max
    }
    float mv = val;
#pragma unroll
    for (int off = 1; off < 64; off <<= 1) mv = fmaxf(mv, __shfl_xor(mv, off));
    if (lane == 0) atomicMax(maxbits, __float_as_uint(mv));
}

// ---- K4: bilateral filter (1 px/thread, proven round-8 form) --------------
template<int KK>
__device__ __forceinline__ void filt_spec(const float* __restrict__ xb, int h, int w,
                                          float nix, float niy, float nir,
                                          bool interiorBlk, float* __restrict__ out, int id) {
    constexpr int P = KK / 2;
    float ex[KK];
#pragma unroll
    for (int j = 0; j < KK; ++j) ex[j] = (float)((j - P) * (j - P)) * nix;
    const float xc = xb[h * HW + w];
    float acc0 = 0.f, ws0 = 0.f, acc1 = 0.f, ws1 = 0.f;
    if (interiorBlk) {
        const float* base = xb + (h - P) * HW + (w - P);
#pragma unroll
        for (int i = 0; i < KK; ++i) {
            const float eyr = (float)((i - P) * (i - P)) * niy;
            const float* row = base + i * HW;
#pragma unroll
            for (int j = 0; j < KK; ++j) {
                const float xv = row[j];
                const float dd = xc - xv;
                const float wg = exp2f(fmaf(dd * dd, nir, eyr + ex[j]));
                if (j & 1) { ws1 += wg; acc1 = fmaf(wg, xv, acc1); }
                else       { ws0 += wg; acc0 = fmaf(wg, xv, acc0); }
            }
        }
    } else {
#pragma unroll
        for (int i = 0; i < KK; ++i) {
            int row = h + i - P;
            row = (row < 0) ? -row : ((row > HW - 1) ? 2 * HW - 2 - row : row);
            const float eyr = (float)((i - P) * (i - P)) * niy;
            const float* rp = xb + row * HW;
#pragma unroll
            for (int j = 0; j < KK; ++j) {
                int col = w + j - P;
                col = (col < 0) ? -col : ((col > HW - 1) ? 2 * HW - 2 - col : col);
                const float xv = rp[col];
                const float dd = xc - xv;
                const float wg = exp2f(fmaf(dd * dd, nir, eyr + ex[j]));
                if (j & 1) { ws1 += wg; acc1 = fmaf(wg, xv, acc1); }
                else       { ws0 += wg; acc0 = fmaf(wg, xv, acc0); }
            }
        }
    }
    out[id] = (acc0 + acc1) / (ws0 + ws1 + 1e-8f);
}

__device__ void filt_generic(const float* __restrict__ xb, int h, int w, int kk,
                             float nix, float niy, float nir,
                             float* __restrict__ out, int id) {
    const int P = kk >> 1;
    const float xc = xb[h * HW + w];
    float acc = 0.f, wsum = 0.f;
    for (int i = 0; i < kk; ++i) {
        int row = h + i - P;
        row = (row < 0) ? -row : ((row > HW - 1) ? 2 * HW - 2 - row : row);
        const float eyr = (float)((i - P) * (i - P)) * niy;
        const float* rp = xb + row * HW;
        for (int j = 0; j < kk; ++j) {
            int col = w + j - P;
            col = (col < 0) ? -col : ((col > HW - 1) ? 2 * HW - 2 - col : col);
            const float xv = rp[col];
            const float dd = xc - xv;
            const float wg = exp2f(fmaf(dd * dd, nir, eyr + (float)((j - P) * (j - P)) * nix));
            wsum += wg;
            acc = fmaf(wg, xv, acc);
        }
    }
    out[id] = acc / (wsum + 1e-8f);
}

__global__ __launch_bounds__(256)
void filter_kernel(const float* __restrict__ x, const float* __restrict__ SP,
                   const unsigned int* __restrict__ maxbits, float* __restrict__ out) {
    const int blk = blockIdx.x;
    const int b = blk >> 10, n = blk & 1023;
    const int ph = n >> 5, pw = n & 31;
    const int tid = threadIdx.x;
    const int h = ph * 16 + (tid >> 4), w = pw * 16 + (tid & 15);
    const int id = b * IMG + h * HW + w;
    const float* xb = x + b * IMG;
    const float* sp = SP + (b * N + n) * 3;
    const float sx = sp[0], sy = sp[1], sr = sp[2];
    constexpr float L2E = 1.4426950408889634f;
    const float nix = -0.5f * L2E / (sx * sx);
    const float niy = -0.5f * L2E / (sy * sy);
    const float nir = -0.5f * L2E / (sr * sr);
    const float m = __uint_as_float(*maxbits);
    int kk = 2 * (int)ceilf(m) + 1;                // always odd
    if (kk < 1) kk = 1;
    if (kk > 31) kk = 31;
    const bool ib = (ph > 0) & (ph < 31) & (pw > 0) & (pw < 31);
    if (kk == 11)      filt_spec<11>(xb, h, w, nix, niy, nir, ib, out, id);
    else if (kk == 9)  filt_spec<9>(xb, h, w, nix, niy, nir, ib, out, id);
    else if (kk == 13) filt_spec<13>(xb, h, w, nix, niy, nir, ib, out, id);
    else if (kk == 7)  filt_spec<7>(xb, h, w, nix, niy, nir, ib, out, id);
    else               filt_generic(xb, h, w, kk, nix, niy, nir, out, id);
}

extern "C" void kernel_launch(void* const* d_in, const int* in_sizes, int n_in,
                              void* d_out, int out_size, void* d_ws, size_t ws_size,
                              hipStream_t stream) {
    const float* x    = (const float*)d_in[0];
    const float* Wq   = (const float*)d_in[1];
    const float* bq   = (const float*)d_in[2];
    const float* Wk   = (const float*)d_in[3];
    const float* bk   = (const float*)d_in[4];
    const float* Wv   = (const float*)d_in[5];
    const float* bv   = (const float*)d_in[6];
    const float* Wsq  = (const float*)d_in[7];
    const float* bsq  = (const float*)d_in[8];
    const float* Wsk  = (const float*)d_in[9];
    const float* bsk  = (const float*)d_in[10];
    const float* Wsv  = (const float*)d_in[11];
    const float* bsv  = (const float*)d_in[12];
    const float* ln_g = (const float*)d_in[13];
    const float* ln_b = (const float*)d_in[14];
    const float* Wp   = (const float*)d_in[15];
    const float* bp   = (const float*)d_in[16];
    float* out = (float*)d_out;

    float* ws = (float*)d_ws;
    float* Q   = ws;                 // 16384 floats
    float* Kf  = ws + 16384;
    float* Vf  = ws + 32768;
    float* SQ  = ws + 49152;
    float* SK  = ws + 65536;
    float* SV  = ws + 81920;
    float* SP  = ws + 98304;         // 6144 floats
    unsigned int* maxbits = (unsigned int*)(ws + 104448);

    qkv_kernel<<<B * N, 256, 0, stream>>>(x, Wq, bq, Wk, bk, Wv, bv, Q, Kf, Vf, maxbits);
    // MEASUREMENT: 9x each attn kernel (idempotent). dur = base + 8*(Tap+Tah+2g).
    for (int r = 0; r < 9; ++r)
        attn_proj_kernel<<<B * N / 8, 256, 0, stream>>>(Q, Kf, Vf, Wsq, bsq, Wsk, bsk, Wsv, bsv, SQ, SK, SV);
    for (int r = 0; r < 9; ++r)
        attn_head_kernel<<<B * N / 8, 256, 0, stream>>>(SQ, SK, SV, ln_g, ln_b, Wp, bp, SP, maxbits);
    filter_kernel<<<B * N, 256, 0, stream>>>(x, SP, maxbits, out);
}

// Round 14
// 55.669 us; speedup vs baseline: 4.7944x; 4.7944x over previous
//
#include <hip/hip_runtime.h>
#include <hip/hip_bf16.h>
#include <math.h>

// ---------------------------------------------------------------------------
// 4-kernel pipeline:
//  K1 qkv_kernel : patchify + 3x linear (256->8), zeroes maxbits      [2048 blk]
//  K2 attn_proj  : attention #1 — 1024-thr blocks (16 waves = 4/SIMD),
//                  4 query-pairs x 4 token-quarters, LDS partial-softmax
//                  combine, fused 3x(8->8) projection                 [256 blk]
//  K3 attn_head  : attention #2 (same core) + LN + head + 1 atomic/blk
//  K4 filter     : bilateral, 1 px/thread, k specialized (VALU-roofline)
// NOTES:
//  - r13 measurement: old 256-thr attn pair = 23us at 1 wave/SIMD (latency-
//    exposed). This version: 4 waves/SIMD, dots cached, 256 atomics not 1024.
//  - no cooperative launch (grid.sync ~100us, r4); no filter reg-blocking
//    (spills, r7); filter is VALU-bound at ~90% busy (r11).
// ---------------------------------------------------------------------------

#define B 2
#define N 1024          // 32x32 patches
#define HW 512
#define IMG (HW*HW)

__device__ __forceinline__ float fexp2(float x) {
#if __has_builtin(__builtin_amdgcn_exp2f)
    return __builtin_amdgcn_exp2f(x);
#else
    return exp2f(x);
#endif
}

// ---- K1: patchify + QKV projection ---------------------------------------
__global__ __launch_bounds__(256)
void qkv_kernel(const float* __restrict__ x,
                const float* __restrict__ Wq, const float* __restrict__ bq,
                const float* __restrict__ Wk, const float* __restrict__ bk,
                const float* __restrict__ Wv, const float* __restrict__ bv,
                float* __restrict__ Q, float* __restrict__ K, float* __restrict__ V,
                unsigned int* __restrict__ maxbits) {
    const int bn = blockIdx.x;
    const int b  = bn >> 10, n = bn & 1023;
    const int ph = n >> 5, pw = n & 31;
    const int tid = threadIdx.x;
    if (bn == 0 && tid == 0) atomicExch(maxbits, 0u);   // fresh every call
    __shared__ float p[256];
    p[tid] = x[b * IMG + (ph * 16 + (tid >> 4)) * HW + pw * 16 + (tid & 15)];
    __syncthreads();
    if (tid < 192) {
        const int o = tid >> 3, sub = tid & 7;   // 24 outputs x 8 partials
        const int mat = o >> 3, j = o & 7;       // wave-uniform mat
        const float* W  = (mat == 0) ? Wq : (mat == 1) ? Wk : Wv;
        const float* bb = (mat == 0) ? bq : (mat == 1) ? bk : bv;
        float sum = 0.f;
#pragma unroll
        for (int dd = 0; dd < 32; ++dd) {
            const int d = dd * 8 + sub;
            sum = fmaf(p[d], W[d * 8 + j], sum);
        }
        sum += __shfl_xor(sum, 1);
        sum += __shfl_xor(sum, 2);
        sum += __shfl_xor(sum, 4);
        if (sub == 0) {
            float* op = (mat == 0) ? Q : (mat == 1) ? K : V;
            op[bn * 8 + j] = sum + bb[j];
        }
    }
}

// ---- attention core: 1024 threads, 16 waves, 8 queries, 1024 tokens -------
// wave w: query-pair p = w&3 (queries q0+2p, q0+2p+1), token-quarter tq = w>>2
// (tokens tq*256 .. +256). Partial (m, s, va[8]) per query per quarter ->
// LDS; tid<8 combines (two-level online softmax) into ff[q][8].
struct AttnLds {
    float Kl[8 * 1024];
    float Vl[8 * 1024];
    float pm[4][4][2];
    float ps[4][4][2];
    float pv[4][4][2][8];
    float ff[8][8];
    float mr[8];
};

__device__ __forceinline__ void attn_core(AttnLds& S,
                                          const float* __restrict__ Qg,
                                          const float* __restrict__ Kb,
                                          const float* __restrict__ Vb,
                                          int q0, int tid) {
    // stage K,V transposed (2 iters/thread, 16 waves -> deep load overlap)
    for (int i = tid; i < 2048; i += 1024) {
        const float4 kv = ((const float4*)Kb)[i];
        const int tok = i >> 1, d0 = (i & 1) * 4;
        S.Kl[(d0 + 0) * 1024 + tok] = kv.x;
        S.Kl[(d0 + 1) * 1024 + tok] = kv.y;
        S.Kl[(d0 + 2) * 1024 + tok] = kv.z;
        S.Kl[(d0 + 3) * 1024 + tok] = kv.w;
        const float4 vv = ((const float4*)Vb)[i];
        S.Vl[(d0 + 0) * 1024 + tok] = vv.x;
        S.Vl[(d0 + 1) * 1024 + tok] = vv.y;
        S.Vl[(d0 + 2) * 1024 + tok] = vv.z;
        S.Vl[(d0 + 3) * 1024 + tok] = vv.w;
    }
    __syncthreads();

    const int w = tid >> 6, lane = tid & 63;
    const int p = w & 3, tq = w >> 2;
    const int qa = q0 + p * 2, qb = qa + 1;
    const int tok0 = tq * 256;

    float qav[8], qbv[8];
#pragma unroll
    for (int d = 0; d < 8; ++d) { qav[d] = Qg[qa * 8 + d]; qbv[d] = Qg[qb * 8 + d]; }

    const float SC = 0.35355339059327373f;     // 8^-0.5
    const float L2E = 1.4426950408889634f;

    // pass 1: dots cached (4 per query), raw max
    float dA[4], dB[4];
    float mxa = -3.0e38f, mxb = -3.0e38f;
#pragma unroll
    for (int t = 0; t < 4; ++t) {
        const int tok = tok0 + t * 64 + lane;
        float da = 0.f, db = 0.f;
#pragma unroll
        for (int d = 0; d < 8; ++d) {
            const float kd = S.Kl[d * 1024 + tok];
            da = fmaf(qav[d], kd, da);
            db = fmaf(qbv[d], kd, db);
        }
        dA[t] = da; dB[t] = db;
        mxa = fmaxf(mxa, da); mxb = fmaxf(mxb, db);
    }
#pragma unroll
    for (int off = 1; off < 64; off <<= 1) {
        mxa = fmaxf(mxa, __shfl_xor(mxa, off));
        mxb = fmaxf(mxb, __shfl_xor(mxb, off));
    }
    mxa *= SC; mxb *= SC;

    // pass 2: exp-sum + weighted V (no K re-read)
    float sa = 0.f, sb = 0.f;
    float va[8] = {0,0,0,0,0,0,0,0}, vb[8] = {0,0,0,0,0,0,0,0};
#pragma unroll
    for (int t = 0; t < 4; ++t) {
        const int tok = tok0 + t * 64 + lane;
        const float ea = fexp2((dA[t] * SC - mxa) * L2E);
        const float eb = fexp2((dB[t] * SC - mxb) * L2E);
        sa += ea; sb += eb;
#pragma unroll
        for (int d = 0; d < 8; ++d) {
            const float vd = S.Vl[d * 1024 + tok];
            va[d] = fmaf(ea, vd, va[d]);
            vb[d] = fmaf(eb, vd, vb[d]);
        }
    }
#pragma unroll
    for (int off = 1; off < 64; off <<= 1) {
        sa += __shfl_xor(sa, off);
        sb += __shfl_xor(sb, off);
#pragma unroll
        for (int d = 0; d < 8; ++d) {
            va[d] += __shfl_xor(va[d], off);
            vb[d] += __shfl_xor(vb[d], off);
        }
    }
    if (lane == 0) {
        S.pm[p][tq][0] = mxa; S.pm[p][tq][1] = mxb;
        S.ps[p][tq][0] = sa;  S.ps[p][tq][1] = sb;
#pragma unroll
        for (int d = 0; d < 8; ++d) {
            S.pv[p][tq][0][d] = va[d];
            S.pv[p][tq][1][d] = vb[d];
        }
    }
    __syncthreads();

    // combine 4 quarters per query (two-level online softmax)
    if (tid < 8) {
        const int pidx = tid >> 1, which = tid & 1;
        float m = S.pm[pidx][0][which];
#pragma unroll
        for (int t = 1; t < 4; ++t) m = fmaxf(m, S.pm[pidx][t][which]);
        float s = 0.f, vd[8] = {0,0,0,0,0,0,0,0};
#pragma unroll
        for (int t = 0; t < 4; ++t) {
            const float f = fexp2((S.pm[pidx][t][which] - m) * L2E);
            s = fmaf(S.ps[pidx][t][which], f, s);
#pragma unroll
            for (int d = 0; d < 8; ++d)
                vd[d] = fmaf(S.pv[pidx][t][which][d], f, vd[d]);
        }
        const float inv = 1.f / s;
#pragma unroll
        for (int d = 0; d < 8; ++d) S.ff[tid][d] = vd[d] * inv;
    }
    __syncthreads();
}

// ---- K2: attention #1 + fused second-stage QKV projection -----------------
__global__ __launch_bounds__(1024)
void attn_proj_kernel(const float* __restrict__ Q, const float* __restrict__ K,
                      const float* __restrict__ V,
                      const float* __restrict__ Wsq, const float* __restrict__ bsq,
                      const float* __restrict__ Wsk, const float* __restrict__ bsk,
                      const float* __restrict__ Wsv, const float* __restrict__ bsv,
                      float* __restrict__ SQ, float* __restrict__ SK, float* __restrict__ SV) {
    __shared__ AttnLds S;
    const int tid = threadIdx.x;
    const int q0 = blockIdx.x * 8;
    const int b  = q0 >> 10;
    attn_core(S, Q, K + (b << 13), V + (b << 13), q0, tid);
    if (tid < 192) {
        const int q = tid / 24, o = tid - q * 24;
        const int mat = o >> 3, j = o & 7;
        const float* W  = (mat == 0) ? Wsq : (mat == 1) ? Wsk : Wsv;
        const float* bb = (mat == 0) ? bsq : (mat == 1) ? bsk : bsv;
        float s = bb[j];
#pragma unroll
        for (int d = 0; d < 8; ++d) s = fmaf(S.ff[q][d], W[d * 8 + j], s);
        float* op = (mat == 0) ? SQ : (mat == 1) ? SK : SV;
        op[(q0 + q) * 8 + j] = s;
    }
}

// ---- K3: attention #2 + fused LN + sigma head + global max ----------------
__global__ __launch_bounds__(1024)
void attn_head_kernel(const float* __restrict__ SQ, const float* __restrict__ SK,
                      const float* __restrict__ SV,
                      const float* __restrict__ g, const float* __restrict__ be,
                      const float* __restrict__ Wp, const float* __restrict__ bp,
                      float* __restrict__ SP, unsigned int* __restrict__ maxbits) {
    __shared__ AttnLds S;
    const int tid = threadIdx.x;
    const int q0 = blockIdx.x * 8;
    const int b  = q0 >> 10;
    attn_core(S, SQ, SK + (b << 13), SV + (b << 13), q0, tid);
    if (tid < 8) {
        const float* f = S.ff[tid];
        float mu = 0.f;
#pragma unroll
        for (int d = 0; d < 8; ++d) mu += f[d];
        mu *= 0.125f;
        float var = 0.f;
#pragma unroll
        for (int d = 0; d < 8; ++d) { const float t = f[d] - mu; var = fmaf(t, t, var); }
        var *= 0.125f;
        const float inv = rsqrtf(var + 1e-5f);
        float mloc = 0.f;
#pragma unroll
        for (int l = 0; l < 3; ++l) {
            float o = bp[l];
#pragma unroll
            for (int d = 0; d < 8; ++d) {
                const float nrm = (f[d] - mu) * inv * g[d] + be[d];
                o = fmaf(nrm, Wp[d * 3 + l], o);
            }
            const float sp = fmaxf(o, 0.f) + log1pf(__expf(-fabsf(o)));
            const float v = fminf(sp, 6.0f) + 1e-6f;
            SP[(q0 + tid) * 3 + l] = v;
            if (l < 2) mloc = fmaxf(mloc, v);
        }
        S.mr[tid] = mloc;
    }
    __syncthreads();
    if (tid == 0) {
        float m = S.mr[0];
#pragma unroll
        for (int i = 1; i < 8; ++i) m = fmaxf(m, S.mr[i]);
        atomicMax(maxbits, __float_as_uint(m));   // 1 atomic per block
    }
}

// ---- K4: bilateral filter (1 px/thread, proven round-8 form) --------------
template<int KK>
__device__ __forceinline__ void filt_spec(const float* __restrict__ xb, int h, int w,
                                          float nix, float niy, float nir,
                                          bool interiorBlk, float* __restrict__ out, int id) {
    constexpr int P = KK / 2;
    float ex[KK];
#pragma unroll
    for (int j = 0; j < KK; ++j) ex[j] = (float)((j - P) * (j - P)) * nix;
    const float xc = xb[h * HW + w];
    float acc0 = 0.f, ws0 = 0.f, acc1 = 0.f, ws1 = 0.f;
    if (interiorBlk) {
        const float* base = xb + (h - P) * HW + (w - P);
#pragma unroll
        for (int i = 0; i < KK; ++i) {
            const float eyr = (float)((i - P) * (i - P)) * niy;
            const float* row = base + i * HW;
#pragma unroll
            for (int j = 0; j < KK; ++j) {
                const float xv = row[j];
                const float dd = xc - xv;
                const float wg = fexp2(fmaf(dd * dd, nir, eyr + ex[j]));
                if (j & 1) { ws1 += wg; acc1 = fmaf(wg, xv, acc1); }
                else       { ws0 += wg; acc0 = fmaf(wg, xv, acc0); }
            }
        }
    } else {
#pragma unroll
        for (int i = 0; i < KK; ++i) {
            int row = h + i - P;
            row = (row < 0) ? -row : ((row > HW - 1) ? 2 * HW - 2 - row : row);
            const float eyr = (float)((i - P) * (i - P)) * niy;
            const float* rp = xb + row * HW;
#pragma unroll
            for (int j = 0; j < KK; ++j) {
                int col = w + j - P;
                col = (col < 0) ? -col : ((col > HW - 1) ? 2 * HW - 2 - col : col);
                const float xv = rp[col];
                const float dd = xc - xv;
                const float wg = fexp2(fmaf(dd * dd, nir, eyr + ex[j]));
                if (j & 1) { ws1 += wg; acc1 = fmaf(wg, xv, acc1); }
                else       { ws0 += wg; acc0 = fmaf(wg, xv, acc0); }
            }
        }
    }
    out[id] = (acc0 + acc1) / (ws0 + ws1 + 1e-8f);
}

__device__ void filt_generic(const float* __restrict__ xb, int h, int w, int kk,
                             float nix, float niy, float nir,
                             float* __restrict__ out, int id) {
    const int P = kk >> 1;
    const float xc = xb[h * HW + w];
    float acc = 0.f, wsum = 0.f;
    for (int i = 0; i < kk; ++i) {
        int row = h + i - P;
        row = (row < 0) ? -row : ((row > HW - 1) ? 2 * HW - 2 - row : row);
        const float eyr = (float)((i - P) * (i - P)) * niy;
        const float* rp = xb + row * HW;
        for (int j = 0; j < kk; ++j) {
            int col = w + j - P;
            col = (col < 0) ? -col : ((col > HW - 1) ? 2 * HW - 2 - col : col);
            const float xv = rp[col];
            const float dd = xc - xv;
            const float wg = fexp2(fmaf(dd * dd, nir, eyr + (float)((j - P) * (j - P)) * nix));
            wsum += wg;
            acc = fmaf(wg, xv, acc);
        }
    }
    out[id] = acc / (wsum + 1e-8f);
}

__global__ __launch_bounds__(256)
void filter_kernel(const float* __restrict__ x, const float* __restrict__ SP,
                   const unsigned int* __restrict__ maxbits, float* __restrict__ out) {
    const int blk = blockIdx.x;
    const int b = blk >> 10, n = blk & 1023;
    const int ph = n >> 5, pw = n & 31;
    const int tid = threadIdx.x;
    const int h = ph * 16 + (tid >> 4), w = pw * 16 + (tid & 15);
    const int id = b * IMG + h * HW + w;
    const float* xb = x + b * IMG;
    const float* sp = SP + (b * N + n) * 3;
    const float sx = sp[0], sy = sp[1], sr = sp[2];
    constexpr float L2E = 1.4426950408889634f;
    const float nix = -0.5f * L2E / (sx * sx);
    const float niy = -0.5f * L2E / (sy * sy);
    const float nir = -0.5f * L2E / (sr * sr);
    const float m = __uint_as_float(*maxbits);
    int kk = 2 * (int)ceilf(m) + 1;                // always odd
    if (kk < 1) kk = 1;
    if (kk > 31) kk = 31;
    const bool ib = (ph > 0) & (ph < 31) & (pw > 0) & (pw < 31);
    if (kk == 11)      filt_spec<11>(xb, h, w, nix, niy, nir, ib, out, id);
    else if (kk == 9)  filt_spec<9>(xb, h, w, nix, niy, nir, ib, out, id);
    else if (kk == 13) filt_spec<13>(xb, h, w, nix, niy, nir, ib, out, id);
    else if (kk == 7)  filt_spec<7>(xb, h, w, nix, niy, nir, ib, out, id);
    else               filt_generic(xb, h, w, kk, nix, niy, nir, out, id);
}

extern "C" void kernel_launch(void* const* d_in, const int* in_sizes, int n_in,
                              void* d_out, int out_size, void* d_ws, size_t ws_size,
                              hipStream_t stream) {
    const float* x    = (const float*)d_in[0];
    const float* Wq   = (const float*)d_in[1];
    const float* bq   = (const float*)d_in[2];
    const float* Wk   = (const float*)d_in[3];
    const float* bk   = (const float*)d_in[4];
    const float* Wv   = (const float*)d_in[5];
    const float* bv   = (const float*)d_in[6];
    const float* Wsq  = (const float*)d_in[7];
    const float* bsq  = (const float*)d_in[8];
    const float* Wsk  = (const float*)d_in[9];
    const float* bsk  = (const float*)d_in[10];
    const float* Wsv  = (const float*)d_in[11];
    const float* bsv  = (const float*)d_in[12];
    const float* ln_g = (const float*)d_in[13];
    const float* ln_b = (const float*)d_in[14];
    const float* Wp   = (const float*)d_in[15];
    const float* bp   = (const float*)d_in[16];
    float* out = (float*)d_out;

    float* ws = (float*)d_ws;
    float* Q   = ws;                 // 16384 floats
    float* Kf  = ws + 16384;
    float* Vf  = ws + 32768;
    float* SQ  = ws + 49152;
    float* SK  = ws + 65536;
    float* SV  = ws + 81920;
    float* SP  = ws + 98304;         // 6144 floats
    unsigned int* maxbits = (unsigned int*)(ws + 104448);

    qkv_kernel<<<B * N, 256, 0, stream>>>(x, Wq, bq, Wk, bk, Wv, bv, Q, Kf, Vf, maxbits);
    attn_proj_kernel<<<B * N / 8, 1024, 0, stream>>>(Q, Kf, Vf, Wsq, bsq, Wsk, bsk, Wsv, bsv, SQ, SK, SV);
    attn_head_kernel<<<B * N / 8, 1024, 0, stream>>>(SQ, SK, SV, ln_g, ln_b, Wp, bp, SP, maxbits);
    filter_kernel<<<B * N, 256, 0, stream>>>(x, SP, maxbits, out);
}

// Round 15
// 53.968 us; speedup vs baseline: 4.9455x; 1.0315x over previous
//
#include <hip/hip_runtime.h>
#include <hip/hip_bf16.h>
#include <math.h>

// ---------------------------------------------------------------------------
// 4-kernel pipeline:
//  K1 qkv_kernel : patchify + 3x linear (256->8), zeroes maxbits      [2048 blk]
//  K2 attn_proj  : attention #1 — 1024-thr blocks, K/V DIRECT TO REGISTERS
//                  (no LDS staging), 4 query-pairs x 4 token-quarters,
//                  tiny-LDS partial-softmax combine, fused projection [256 blk]
//  K3 attn_head  : attention #2 (same core) + LN + head + 1 atomic/blk
//  K4 filter     : bilateral, 1 px/thread, k specialized (VALU-roofline)
// NOTES:
//  - r14: LDS-staged attn = ~6us/kernel; staging round-trip dominated.
//    This version: per-lane K rows (4 toks x 2 float4) load straight to VGPRs,
//    K regs die before V regs live (peak ~100 VGPR < 128 cap at 1024 thr).
//  - filter at VALU roofline (r11: 90% busy); envelope ~18us harness-fixed.
//  - no cooperative launch (grid.sync ~100us, r4); no filter reg-block (r7).
// ---------------------------------------------------------------------------

#define B 2
#define N 1024          // 32x32 patches
#define HW 512
#define IMG (HW*HW)

__device__ __forceinline__ float fexp2(float x) {
#if __has_builtin(__builtin_amdgcn_exp2f)
    return __builtin_amdgcn_exp2f(x);
#else
    return exp2f(x);
#endif
}

// ---- K1: patchify + QKV projection ---------------------------------------
__global__ __launch_bounds__(256)
void qkv_kernel(const float* __restrict__ x,
                const float* __restrict__ Wq, const float* __restrict__ bq,
                const float* __restrict__ Wk, const float* __restrict__ bk,
                const float* __restrict__ Wv, const float* __restrict__ bv,
                float* __restrict__ Q, float* __restrict__ K, float* __restrict__ V,
                unsigned int* __restrict__ maxbits) {
    const int bn = blockIdx.x;
    const int b  = bn >> 10, n = bn & 1023;
    const int ph = n >> 5, pw = n & 31;
    const int tid = threadIdx.x;
    if (bn == 0 && tid == 0) atomicExch(maxbits, 0u);   // fresh every call
    __shared__ float p[256];
    p[tid] = x[b * IMG + (ph * 16 + (tid >> 4)) * HW + pw * 16 + (tid & 15)];
    __syncthreads();
    if (tid < 192) {
        const int o = tid >> 3, sub = tid & 7;   // 24 outputs x 8 partials
        const int mat = o >> 3, j = o & 7;       // wave-uniform mat
        const float* W  = (mat == 0) ? Wq : (mat == 1) ? Wk : Wv;
        const float* bb = (mat == 0) ? bq : (mat == 1) ? bk : bv;
        float sum = 0.f;
#pragma unroll
        for (int dd = 0; dd < 32; ++dd) {
            const int d = dd * 8 + sub;
            sum = fmaf(p[d], W[d * 8 + j], sum);
        }
        sum += __shfl_xor(sum, 1);
        sum += __shfl_xor(sum, 2);
        sum += __shfl_xor(sum, 4);
        if (sub == 0) {
            float* op = (mat == 0) ? Q : (mat == 1) ? K : V;
            op[bn * 8 + j] = sum + bb[j];
        }
    }
}

// ---- attention core: 1024 threads, K/V in registers, tiny-LDS combine -----
// wave w: query-pair p = w&3 (queries q0+2p, q0+2p+1), token-quarter tq = w>>2.
// Each lane owns 4 tokens (tok0 + t*64 + lane); K/V rows are 2 float4 each,
// loaded straight to VGPRs. Partials (m,s,va[8]) -> LDS; tid<8 combines.
struct AttnLds {
    float pm[4][4][2];
    float ps[4][4][2];
    float pv[4][4][2][8];
    float ff[8][8];
    float mr[8];
};

__device__ __forceinline__ void attn_core(AttnLds& S,
                                          const float* __restrict__ Qg,
                                          const float* __restrict__ Kb,
                                          const float* __restrict__ Vb,
                                          int q0, int tid) {
    const int w = tid >> 6, lane = tid & 63;
    const int p = w & 3, tq = w >> 2;
    const int qa = q0 + p * 2, qb = qa + 1;
    const int tok0 = tq * 256;

    float qav[8], qbv[8];
#pragma unroll
    for (int d = 0; d < 8; ++d) { qav[d] = Qg[qa * 8 + d]; qbv[d] = Qg[qb * 8 + d]; }

    const float SC = 0.35355339059327373f;     // 8^-0.5
    const float L2E = 1.4426950408889634f;

    // pass 1: K rows direct to registers, dots cached, raw max
    float dA[4], dB[4];
    float mxa = -3.0e38f, mxb = -3.0e38f;
#pragma unroll
    for (int t = 0; t < 4; ++t) {
        const int tok = tok0 + t * 64 + lane;
        const float4 k0 = ((const float4*)Kb)[tok * 2];
        const float4 k1 = ((const float4*)Kb)[tok * 2 + 1];
        float da = qav[0] * k0.x, db = qbv[0] * k0.x;
        da = fmaf(qav[1], k0.y, da); db = fmaf(qbv[1], k0.y, db);
        da = fmaf(qav[2], k0.z, da); db = fmaf(qbv[2], k0.z, db);
        da = fmaf(qav[3], k0.w, da); db = fmaf(qbv[3], k0.w, db);
        da = fmaf(qav[4], k1.x, da); db = fmaf(qbv[4], k1.x, db);
        da = fmaf(qav[5], k1.y, da); db = fmaf(qbv[5], k1.y, db);
        da = fmaf(qav[6], k1.z, da); db = fmaf(qbv[6], k1.z, db);
        da = fmaf(qav[7], k1.w, da); db = fmaf(qbv[7], k1.w, db);
        dA[t] = da; dB[t] = db;
        mxa = fmaxf(mxa, da); mxb = fmaxf(mxb, db);
    }
#pragma unroll
    for (int off = 1; off < 64; off <<= 1) {
        mxa = fmaxf(mxa, __shfl_xor(mxa, off));
        mxb = fmaxf(mxb, __shfl_xor(mxb, off));
    }
    mxa *= SC; mxb *= SC;

    // pass 2: V rows direct to registers (K regs dead -> reused)
    float sa = 0.f, sb = 0.f;
    float va[8] = {0,0,0,0,0,0,0,0}, vb[8] = {0,0,0,0,0,0,0,0};
#pragma unroll
    for (int t = 0; t < 4; ++t) {
        const int tok = tok0 + t * 64 + lane;
        const float4 v0 = ((const float4*)Vb)[tok * 2];
        const float4 v1 = ((const float4*)Vb)[tok * 2 + 1];
        const float ea = fexp2((dA[t] * SC - mxa) * L2E);
        const float eb = fexp2((dB[t] * SC - mxb) * L2E);
        sa += ea; sb += eb;
        va[0] = fmaf(ea, v0.x, va[0]); vb[0] = fmaf(eb, v0.x, vb[0]);
        va[1] = fmaf(ea, v0.y, va[1]); vb[1] = fmaf(eb, v0.y, vb[1]);
        va[2] = fmaf(ea, v0.z, va[2]); vb[2] = fmaf(eb, v0.z, vb[2]);
        va[3] = fmaf(ea, v0.w, va[3]); vb[3] = fmaf(eb, v0.w, vb[3]);
        va[4] = fmaf(ea, v1.x, va[4]); vb[4] = fmaf(eb, v1.x, vb[4]);
        va[5] = fmaf(ea, v1.y, va[5]); vb[5] = fmaf(eb, v1.y, vb[5]);
        va[6] = fmaf(ea, v1.z, va[6]); vb[6] = fmaf(eb, v1.z, vb[6]);
        va[7] = fmaf(ea, v1.w, va[7]); vb[7] = fmaf(eb, v1.w, vb[7]);
    }
#pragma unroll
    for (int off = 1; off < 64; off <<= 1) {
        sa += __shfl_xor(sa, off);
        sb += __shfl_xor(sb, off);
#pragma unroll
        for (int d = 0; d < 8; ++d) {
            va[d] += __shfl_xor(va[d], off);
            vb[d] += __shfl_xor(vb[d], off);
        }
    }
    if (lane == 0) {
        S.pm[p][tq][0] = mxa; S.pm[p][tq][1] = mxb;
        S.ps[p][tq][0] = sa;  S.ps[p][tq][1] = sb;
#pragma unroll
        for (int d = 0; d < 8; ++d) {
            S.pv[p][tq][0][d] = va[d];
            S.pv[p][tq][1][d] = vb[d];
        }
    }
    __syncthreads();

    // combine 4 quarters per query (two-level online softmax)
    if (tid < 8) {
        const int pidx = tid >> 1, which = tid & 1;
        float m = S.pm[pidx][0][which];
#pragma unroll
        for (int t = 1; t < 4; ++t) m = fmaxf(m, S.pm[pidx][t][which]);
        float s = 0.f, vd[8] = {0,0,0,0,0,0,0,0};
#pragma unroll
        for (int t = 0; t < 4; ++t) {
            const float f = fexp2((S.pm[pidx][t][which] - m) * L2E);
            s = fmaf(S.ps[pidx][t][which], f, s);
#pragma unroll
            for (int d = 0; d < 8; ++d)
                vd[d] = fmaf(S.pv[pidx][t][which][d], f, vd[d]);
        }
        const float inv = 1.f / s;
#pragma unroll
        for (int d = 0; d < 8; ++d) S.ff[tid][d] = vd[d] * inv;
    }
    __syncthreads();
}

// ---- K2: attention #1 + fused second-stage QKV projection -----------------
__global__ __launch_bounds__(1024)
void attn_proj_kernel(const float* __restrict__ Q, const float* __restrict__ K,
                      const float* __restrict__ V,
                      const float* __restrict__ Wsq, const float* __restrict__ bsq,
                      const float* __restrict__ Wsk, const float* __restrict__ bsk,
                      const float* __restrict__ Wsv, const float* __restrict__ bsv,
                      float* __restrict__ SQ, float* __restrict__ SK, float* __restrict__ SV) {
    __shared__ AttnLds S;
    const int tid = threadIdx.x;
    const int q0 = blockIdx.x * 8;
    const int b  = q0 >> 10;
    attn_core(S, Q, K + (b << 13), V + (b << 13), q0, tid);
    if (tid < 192) {
        const int q = tid / 24, o = tid - q * 24;
        const int mat = o >> 3, j = o & 7;
        const float* W  = (mat == 0) ? Wsq : (mat == 1) ? Wsk : Wsv;
        const float* bb = (mat == 0) ? bsq : (mat == 1) ? bsk : bsv;
        float s = bb[j];
#pragma unroll
        for (int d = 0; d < 8; ++d) s = fmaf(S.ff[q][d], W[d * 8 + j], s);
        float* op = (mat == 0) ? SQ : (mat == 1) ? SK : SV;
        op[(q0 + q) * 8 + j] = s;
    }
}

// ---- K3: attention #2 + fused LN + sigma head + global max ----------------
__global__ __launch_bounds__(1024)
void attn_head_kernel(const float* __restrict__ SQ, const float* __restrict__ SK,
                      const float* __restrict__ SV,
                      const float* __restrict__ g, const float* __restrict__ be,
                      const float* __restrict__ Wp, const float* __restrict__ bp,
                      float* __restrict__ SP, unsigned int* __restrict__ maxbits) {
    __shared__ AttnLds S;
    const int tid = threadIdx.x;
    const int q0 = blockIdx.x * 8;
    const int b  = q0 >> 10;
    attn_core(S, SQ, SK + (b << 13), SV + (b << 13), q0, tid);
    if (tid < 8) {
        const float* f = S.ff[tid];
        float mu = 0.f;
#pragma unroll
        for (int d = 0; d < 8; ++d) mu += f[d];
        mu *= 0.125f;
        float var = 0.f;
#pragma unroll
        for (int d = 0; d < 8; ++d) { const float t = f[d] - mu; var = fmaf(t, t, var); }
        var *= 0.125f;
        const float inv = rsqrtf(var + 1e-5f);
        float mloc = 0.f;
#pragma unroll
        for (int l = 0; l < 3; ++l) {
            float o = bp[l];
#pragma unroll
            for (int d = 0; d < 8; ++d) {
                const float nrm = (f[d] - mu) * inv * g[d] + be[d];
                o = fmaf(nrm, Wp[d * 3 + l], o);
            }
            const float sp = fmaxf(o, 0.f) + log1pf(__expf(-fabsf(o)));
            const float v = fminf(sp, 6.0f) + 1e-6f;
            SP[(q0 + tid) * 3 + l] = v;
            if (l < 2) mloc = fmaxf(mloc, v);
        }
        S.mr[tid] = mloc;
    }
    __syncthreads();
    if (tid == 0) {
        float m = S.mr[0];
#pragma unroll
        for (int i = 1; i < 8; ++i) m = fmaxf(m, S.mr[i]);
        atomicMax(maxbits, __float_as_uint(m));   // 1 atomic per block
    }
}

// ---- K4: bilateral filter (1 px/thread, proven round-8 form) --------------
template<int KK>
__device__ __forceinline__ void filt_spec(const float* __restrict__ xb, int h, int w,
                                          float nix, float niy, float nir,
                                          bool interiorBlk, float* __restrict__ out, int id) {
    constexpr int P = KK / 2;
    float ex[KK];
#pragma unroll
    for (int j = 0; j < KK; ++j) ex[j] = (float)((j - P) * (j - P)) * nix;
    const float xc = xb[h * HW + w];
    float acc0 = 0.f, ws0 = 0.f, acc1 = 0.f, ws1 = 0.f;
    if (interiorBlk) {
        const float* base = xb + (h - P) * HW + (w - P);
#pragma unroll
        for (int i = 0; i < KK; ++i) {
            const float eyr = (float)((i - P) * (i - P)) * niy;
            const float* row = base + i * HW;
#pragma unroll
            for (int j = 0; j < KK; ++j) {
                const float xv = row[j];
                const float dd = xc - xv;
                const float wg = fexp2(fmaf(dd * dd, nir, eyr + ex[j]));
                if (j & 1) { ws1 += wg; acc1 = fmaf(wg, xv, acc1); }
                else       { ws0 += wg; acc0 = fmaf(wg, xv, acc0); }
            }
        }
    } else {
#pragma unroll
        for (int i = 0; i < KK; ++i) {
            int row = h + i - P;
            row = (row < 0) ? -row : ((row > HW - 1) ? 2 * HW - 2 - row : row);
            const float eyr = (float)((i - P) * (i - P)) * niy;
            const float* rp = xb + row * HW;
#pragma unroll
            for (int j = 0; j < KK; ++j) {
                int col = w + j - P;
                col = (col < 0) ? -col : ((col > HW - 1) ? 2 * HW - 2 - col : col);
                const float xv = rp[col];
                const float dd = xc - xv;
                const float wg = fexp2(fmaf(dd * dd, nir, eyr + ex[j]));
                if (j & 1) { ws1 += wg; acc1 = fmaf(wg, xv, acc1); }
                else       { ws0 += wg; acc0 = fmaf(wg, xv, acc0); }
            }
        }
    }
    out[id] = (acc0 + acc1) / (ws0 + ws1 + 1e-8f);
}

__device__ void filt_generic(const float* __restrict__ xb, int h, int w, int kk,
                             float nix, float niy, float nir,
                             float* __restrict__ out, int id) {
    const int P = kk >> 1;
    const float xc = xb[h * HW + w];
    float acc = 0.f, wsum = 0.f;
    for (int i = 0; i < kk; ++i) {
        int row = h + i - P;
        row = (row < 0) ? -row : ((row > HW - 1) ? 2 * HW - 2 - row : row);
        const float eyr = (float)((i - P) * (i - P)) * niy;
        const float* rp = xb + row * HW;
        for (int j = 0; j < kk; ++j) {
            int col = w + j - P;
            col = (col < 0) ? -col : ((col > HW - 1) ? 2 * HW - 2 - col : col);
            const float xv = rp[col];
            const float dd = xc - xv;
            const float wg = fexp2(fmaf(dd * dd, nir, eyr + (float)((j - P) * (j - P)) * nix));
            wsum += wg;
            acc = fmaf(wg, xv, acc);
        }
    }
    out[id] = acc / (wsum + 1e-8f);
}

__global__ __launch_bounds__(256)
void filter_kernel(const float* __restrict__ x, const float* __restrict__ SP,
                   const unsigned int* __restrict__ maxbits, float* __restrict__ out) {
    const int blk = blockIdx.x;
    const int b = blk >> 10, n = blk & 1023;
    const int ph = n >> 5, pw = n & 31;
    const int tid = threadIdx.x;
    const int h = ph * 16 + (tid >> 4), w = pw * 16 + (tid & 15);
    const int id = b * IMG + h * HW + w;
    const float* xb = x + b * IMG;
    const float* sp = SP + (b * N + n) * 3;
    const float sx = sp[0], sy = sp[1], sr = sp[2];
    constexpr float L2E = 1.4426950408889634f;
    const float nix = -0.5f * L2E / (sx * sx);
    const float niy = -0.5f * L2E / (sy * sy);
    const float nir = -0.5f * L2E / (sr * sr);
    const float m = __uint_as_float(*maxbits);
    int kk = 2 * (int)ceilf(m) + 1;                // always odd
    if (kk < 1) kk = 1;
    if (kk > 31) kk = 31;
    const bool ib = (ph > 0) & (ph < 31) & (pw > 0) & (pw < 31);
    if (kk == 11)      filt_spec<11>(xb, h, w, nix, niy, nir, ib, out, id);
    else if (kk == 9)  filt_spec<9>(xb, h, w, nix, niy, nir, ib, out, id);
    else if (kk == 13) filt_spec<13>(xb, h, w, nix, niy, nir, ib, out, id);
    else if (kk == 7)  filt_spec<7>(xb, h, w, nix, niy, nir, ib, out, id);
    else               filt_generic(xb, h, w, kk, nix, niy, nir, out, id);
}

extern "C" void kernel_launch(void* const* d_in, const int* in_sizes, int n_in,
                              void* d_out, int out_size, void* d_ws, size_t ws_size,
                              hipStream_t stream) {
    const float* x    = (const float*)d_in[0];
    const float* Wq   = (const float*)d_in[1];
    const float* bq   = (const float*)d_in[2];
    const float* Wk   = (const float*)d_in[3];
    const float* bk   = (const float*)d_in[4];
    const float* Wv   = (const float*)d_in[5];
    const float* bv   = (const float*)d_in[6];
    const float* Wsq  = (const float*)d_in[7];
    const float* bsq  = (const float*)d_in[8];
    const float* Wsk  = (const float*)d_in[9];
    const float* bsk  = (const float*)d_in[10];
    const float* Wsv  = (const float*)d_in[11];
    const float* bsv  = (const float*)d_in[12];
    const float* ln_g = (const float*)d_in[13];
    const float* ln_b = (const float*)d_in[14];
    const float* Wp   = (const float*)d_in[15];
    const float* bp   = (const float*)d_in[16];
    float* out = (float*)d_out;

    float* ws = (float*)d_ws;
    float* Q   = ws;                 // 16384 floats
    float* Kf  = ws + 16384;
    float* Vf  = ws + 32768;
    float* SQ  = ws + 49152;
    float* SK  = ws + 65536;
    float* SV  = ws + 81920;
    float* SP  = ws + 98304;         // 6144 floats
    unsigned int* maxbits = (unsigned int*)(ws + 104448);

    qkv_kernel<<<B * N, 256, 0, stream>>>(x, Wq, bq, Wk, bk, Wv, bv, Q, Kf, Vf, maxbits);
    attn_proj_kernel<<<B * N / 8, 1024, 0, stream>>>(Q, Kf, Vf, Wsq, bsq, Wsk, bsk, Wsv, bsv, SQ, SK, SV);
    attn_head_kernel<<<B * N / 8, 1024, 0, stream>>>(SQ, SK, SV, ln_g, ln_b, Wp, bp, SP, maxbits);
    filter_kernel<<<B * N, 256, 0, stream>>>(x, SP, maxbits, out);
}